// Round 4
// baseline (2671.565 us; speedup 1.0000x reference)
//
#include <hip/hip_runtime.h>
#include <hip/hip_bf16.h>
#include <math.h>

#define BB 128
#define TT 1024
#define DIN 64
#define HH 256
#define EE 32
#define BT (BB * TT)

typedef unsigned int uint;
typedef unsigned char uchar;

__device__ __forceinline__ int dot4(uint a, uint b, int c) {
  return __builtin_amdgcn_sdot4((int)a, (int)b, c, false);
}
__device__ __forceinline__ unsigned bf16rne(float f) {
  unsigned u = __float_as_uint(f);
  return (u + 0x7fffu + ((u >> 16) & 1u)) >> 16;
}
__device__ __forceinline__ unsigned packbf(float a, float b) {
  return bf16rne(a) | (bf16rne(b) << 16);
}
__device__ __forceinline__ float blo(uint u) { return __uint_as_float(u << 16); }
__device__ __forceinline__ float bhi(uint u) { return __uint_as_float(u & 0xffff0000u); }
__device__ __forceinline__ float rcp_f(float x) { return __builtin_amdgcn_rcpf(x); }
__device__ __forceinline__ float sigm(float x) { return rcp_f(1.0f + __expf(-x)); }
__device__ __forceinline__ float tanh_f(float x) {
  return 1.0f - 2.0f * rcp_f(__expf(2.0f * x) + 1.0f);
}

// ---------- Wfold = W_proj @ W_ih (fp32) ----------
__global__ void fold_f32(const float* __restrict__ Wproj, const float* __restrict__ Wih,
                         float* __restrict__ Wfold) {
  int idx = blockIdx.x * blockDim.x + threadIdx.x;
  if (idx >= 64 * 1024) return;
  int d = idx >> 10, n = idx & 1023;
  float a = 0.f;
  for (int k = 0; k < 256; ++k) a += Wproj[d * 256 + k] * Wih[k * 1024 + n];
  Wfold[d * 1024 + n] = a;
}

// bfold[n] = b_proj @ W_ih + b_lstm
__global__ void bfold_kernel(const float* __restrict__ bproj, const float* __restrict__ Wih,
                             const float* __restrict__ blstm, float* __restrict__ bfold) {
  int n = blockIdx.x * blockDim.x + threadIdx.x;
  if (n >= 1024) return;
  float a = blstm[n];
  for (int k = 0; k < 256; ++k) a += bproj[k] * Wih[k * 1024 + n];
  bfold[n] = a;
}

// ---------- quantize all weight matrices with per-matrix (uniform) scales ----------
// Fragment layouts match the scan's 4-way K-split reads exactly.
// WhQ uint idx = ((c*4)+q)*16 + m*4 + mm, c in [0,1280): c<1024 = Whh col, else Whg col c-1024.
//   covers rows k = q*64 + m*16 + mm*4 + {0..3}.
// XQ uint idx = c*16 + q*4 + mm, c<1024 = Wfold col, else Wmk col. rows k = q*16+mm*4+{0..3}.
// EQ uint idx = c*8 + q*2 + mm. rows k = q*8 + mm*4 + {0..3}.
__global__ __launch_bounds__(1024) void quant_all(
    const float* __restrict__ Whh, const float* __restrict__ Whg,
    const float* __restrict__ Wfold, const float* __restrict__ Wmk,
    const float* __restrict__ We,
    uint* __restrict__ WhQ, uint* __restrict__ XQ, uint* __restrict__ EQ,
    float* __restrict__ scales) {
  const int bid = blockIdx.x, tid = threadIdx.x;
  const float* src;
  int nelem;
  switch (bid) {
    case 0: src = Whh;   nelem = 262144; break;
    case 1: src = Whg;   nelem = 65536;  break;
    case 2: src = Wfold; nelem = 65536;  break;
    case 3: src = Wmk;   nelem = 16384;  break;
    default: src = We;   nelem = 8192;   break;
  }
  float m = 0.f;
  for (int i = tid; i < nelem; i += 1024) m = fmaxf(m, fabsf(src[i]));
#pragma unroll
  for (int d = 1; d < 64; d <<= 1) m = fmaxf(m, __shfl_xor(m, d));
  __shared__ float wm[16];
  if ((tid & 63) == 0) wm[tid >> 6] = m;
  __syncthreads();
  float mg = wm[0];
#pragma unroll
  for (int i = 1; i < 16; ++i) mg = fmaxf(mg, wm[i]);
  mg = fmaxf(mg, 1e-8f);
  if (tid == 0) scales[bid] = mg * (1.0f / 127.0f);
  const float inv = 127.0f / mg;

  if (bid == 0) {  // Whh [256][1024] -> WhQ[0..65536)
    for (int i = tid; i < 65536; i += 1024) {
      int C = i >> 4, r = i & 15;
      int c = C >> 2, q = C & 3, mI = r >> 2, mm = r & 3;
      int k4 = q * 16 + mI * 4 + mm;
      uint d = 0;
#pragma unroll
      for (int bb = 0; bb < 4; ++bb) {
        int qv = __float2int_rn(Whh[(4 * k4 + bb) * 1024 + c] * inv);
        qv = max(-127, min(127, qv));
        d |= ((uint)(qv & 0xff)) << (8 * bb);
      }
      WhQ[i] = d;
    }
  } else if (bid == 1) {  // Whg [256][256] -> WhQ[65536..81920)
    for (int i = tid; i < 16384; i += 1024) {
      int j = i >> 6, rr = i & 63;
      int q = rr >> 4, mI = (rr >> 2) & 3, mm = rr & 3;
      int k4 = q * 16 + mI * 4 + mm;
      uint d = 0;
#pragma unroll
      for (int bb = 0; bb < 4; ++bb) {
        int qv = __float2int_rn(Whg[(4 * k4 + bb) * 256 + j] * inv);
        qv = max(-127, min(127, qv));
        d |= ((uint)(qv & 0xff)) << (8 * bb);
      }
      WhQ[65536 + i] = d;
    }
  } else if (bid == 2) {  // Wfold [64][1024] -> XQ[0..16384)
    for (int i = tid; i < 16384; i += 1024) {
      int c = i >> 4, r = i & 15;
      int q = r >> 2, mm = r & 3;
      int k4 = q * 4 + mm;
      uint d = 0;
#pragma unroll
      for (int bb = 0; bb < 4; ++bb) {
        int qv = __float2int_rn(Wfold[(4 * k4 + bb) * 1024 + c] * inv);
        qv = max(-127, min(127, qv));
        d |= ((uint)(qv & 0xff)) << (8 * bb);
      }
      XQ[i] = d;
    }
  } else if (bid == 3) {  // Wmk [64][256] -> XQ[16384..20480)
    for (int i = tid; i < 4096; i += 1024) {
      int j = i >> 4, r = i & 15;
      int q = r >> 2, mm = r & 3;
      int k4 = q * 4 + mm;
      uint d = 0;
#pragma unroll
      for (int bb = 0; bb < 4; ++bb) {
        int qv = __float2int_rn(Wmk[(4 * k4 + bb) * 256 + j] * inv);
        qv = max(-127, min(127, qv));
        d |= ((uint)(qv & 0xff)) << (8 * bb);
      }
      XQ[16384 + i] = d;
    }
  } else {  // We [32][256] -> EQ[0..2048)
    for (int i = tid; i < 2048; i += 1024) {
      int c = i >> 3, r = i & 7;
      int q = r >> 1, mm = r & 1;
      int k4 = q * 2 + mm;
      uint d = 0;
#pragma unroll
      for (int bb = 0; bb < 4; ++bb) {
        int qv = __float2int_rn(We[(4 * k4 + bb) * 256 + c] * inv);
        qv = max(-127, min(127, qv));
        d |= ((uint)(qv & 0xff)) << (8 * bb);
      }
      EQ[i] = d;
    }
  }
}

// ---------- pack Wp1 [256][128] -> bf16 k-pairs: WQ[j*128 + kp] ----------
__global__ void pack_wp1(const float* __restrict__ Wp1, uint* __restrict__ WQ) {
  int idx = blockIdx.x * blockDim.x + threadIdx.x;
  if (idx >= 16384) return;
  int j = idx >> 7, kp = idx & 127;
  WQ[idx] = packbf(Wp1[(2 * kp) * 128 + j], Wp1[(2 * kp + 1) * 128 + j]);
}

// ---------- per-(b,t) input quantization + scl={xsc,esc,fac,0} ----------
__global__ __launch_bounds__(256) void prep_inputs(
    const float* __restrict__ x, const float* __restrict__ ev, const float* __restrict__ td,
    const float* __restrict__ decay, uint* __restrict__ xq, uint* __restrict__ eq,
    float4* __restrict__ scl) {
  int wid = threadIdx.x >> 6, lane = threadIdx.x & 63;
  int bt = blockIdx.x * 4 + wid;
  if (bt >= BT) return;
  float xv = x[(size_t)bt * DIN + lane];
  float evv = (lane < EE) ? ev[(size_t)bt * EE + lane] : 0.0f;
  float ax = fabsf(xv), ae = fabsf(evv);
#pragma unroll
  for (int m = 1; m < 64; m <<= 1) {
    ax = fmaxf(ax, __shfl_xor(ax, m));
    ae = fmaxf(ae, __shfl_xor(ae, m));
  }
  float mgx = fmaxf(ax, 1e-8f), mge = fmaxf(ae, 1e-8f);
  int qx = __float2int_rn(xv * (127.0f / mgx));
  qx = max(-127, min(127, qx));
  int qe = __float2int_rn(evv * (127.0f / mge));
  qe = max(-127, min(127, qe));
  uint dx = 0, de = 0;
#pragma unroll
  for (int b = 0; b < 4; ++b) dx |= ((uint)(__shfl(qx, lane * 4 + b) & 0xff)) << (8 * b);
#pragma unroll
  for (int b = 0; b < 4; ++b) de |= ((uint)(__shfl(qe, lane * 4 + b) & 0xff)) << (8 * b);
  if (lane < 16) xq[(size_t)bt * 16 + lane] = dx;
  if (lane < 8) eq[(size_t)bt * 8 + lane] = de;
  if (lane == 0) {
    float sp = log1pf(__expf(decay[0]));
    scl[bt] = make_float4(mgx * (1.0f / 127.0f), mge * (1.0f / 127.0f),
                          __expf(-sp * td[bt]), 0.0f);
  }
}

// ---------- output 2: first temporal difference ----------
__global__ void d1_kernel(const float* __restrict__ x, float* __restrict__ out2) {
  int idx = blockIdx.x * blockDim.x + threadIdx.x;
  const int per_t = DIN / 4;
  if (idx >= BB * TT * per_t) return;
  int t = (idx / per_t) % TT;
  float4 cur = reinterpret_cast<const float4*>(x)[idx];
  float4 res;
  if (t == 0) {
    res = make_float4(0.f, 0.f, 0.f, 0.f);
  } else {
    float4 prv = reinterpret_cast<const float4*>(x)[idx - per_t];
    res = make_float4(cur.x - prv.x, cur.y - prv.y, cur.z - prv.z, cur.w - prv.w);
  }
  reinterpret_cast<float4*>(out2)[idx] = res;
}

// ---------- the scan: 1 block/row, 1024 threads; lane quad (j, q=0..3) splits K 4 ways ----------
__global__ __launch_bounds__(1024, 4) void scan_i8(
    const uint* __restrict__ WhQ, const uint* __restrict__ XQ, const uint* __restrict__ EQ,
    const float* __restrict__ scales, const float* __restrict__ bfold,
    const float* __restrict__ bhg, const float* __restrict__ bmk, const float* __restrict__ be,
    const uint* __restrict__ xq, const uint* __restrict__ eqp,
    const float4* __restrict__ scl, float* __restrict__ feat) {
  __shared__ __align__(16) uint XwL[20480];  // 80 KB: ifgo-x + mk, frag layout
  __shared__ __align__(16) uint EwL[2048];   //  8 KB: We frag layout
  __shared__ __align__(16) uint hqW[128];    // 512 B: double-buffered int8 h

  const int tid = threadIdx.x, b = blockIdx.x;
  const int j = tid >> 2, q = tid & 3;
  uchar* hqB = (uchar*)hqW;

  for (int i = tid; i < 20480 / 4; i += 1024) ((uint4*)XwL)[i] = ((const uint4*)XQ)[i];
  for (int i = tid; i < 2048 / 4; i += 1024) ((uint4*)EwL)[i] = ((const uint4*)EQ)[i];
  if (tid < 64) hqW[tid] = 0;  // h(0) = 0 in buffer 0

  // h-side weights (ifgo + hg), this thread's K-quarter: 5 x 4 uint4 = 80 VGPRs
  uint4 wh[5][4];
  const uint4* wsrc = (const uint4*)WhQ;
#pragma unroll
  for (int g = 0; g < 5; ++g) {
    const int base = ((g * 256 + j) * 4 + q) * 4;  // uint4 index
#pragma unroll
    for (int m = 0; m < 4; ++m) wh[g][m] = wsrc[base + m];
  }

  // uniform scales (SGPR) — fold the fixed h-scale 1/127 into the h-side factors
  const float kHH = scales[0] * (1.0f / 127.0f);
  const float kHG = scales[1] * (1.0f / 127.0f);
  const float sXF = scales[2], sMK = scales[3], sE = scales[4];

  const float bf0 = bfold[j], bf1 = bfold[256 + j], bf2 = bfold[512 + j], bf3 = bfold[768 + j];
  const float bhgv = bhg[j], bmkv = bmk[j], bev = be[j];

  float c = 0.0f;
  int buf = 0;
  const uint4* xq4 = (const uint4*)xq;
  const uint2* eq2 = (const uint2*)eqp;
  __syncthreads();

  for (int t = 0; t < TT; ++t) {
    const int bt = b * TT + t;
    const uint4 X0 = xq4[bt * 4 + q];      // x int8, this quarter (16 bytes)
    const uint2 E0 = eq2[bt * 4 + q];      // e int8, this quarter (8 bytes)
    const float4 sv = scl[bt];

    // h-part: 5 gates x K=64 (this quarter); hq reads are wave-broadcast
    int a0 = 0, a1 = 0, a2 = 0, a3 = 0, a4 = 0;
    const uint4* hp = (const uint4*)(hqB + buf * 256 + q * 64);
#pragma unroll
    for (int m = 0; m < 4; ++m) {
      const uint4 hv = hp[m];
      a0 = dot4(wh[0][m].x, hv.x, a0); a0 = dot4(wh[0][m].y, hv.y, a0);
      a0 = dot4(wh[0][m].z, hv.z, a0); a0 = dot4(wh[0][m].w, hv.w, a0);
      a1 = dot4(wh[1][m].x, hv.x, a1); a1 = dot4(wh[1][m].y, hv.y, a1);
      a1 = dot4(wh[1][m].z, hv.z, a1); a1 = dot4(wh[1][m].w, hv.w, a1);
      a2 = dot4(wh[2][m].x, hv.x, a2); a2 = dot4(wh[2][m].y, hv.y, a2);
      a2 = dot4(wh[2][m].z, hv.z, a2); a2 = dot4(wh[2][m].w, hv.w, a2);
      a3 = dot4(wh[3][m].x, hv.x, a3); a3 = dot4(wh[3][m].y, hv.y, a3);
      a3 = dot4(wh[3][m].z, hv.z, a3); a3 = dot4(wh[3][m].w, hv.w, a3);
      a4 = dot4(wh[4][m].x, hv.x, a4); a4 = dot4(wh[4][m].y, hv.y, a4);
      a4 = dot4(wh[4][m].z, hv.z, a4); a4 = dot4(wh[4][m].w, hv.w, a4);
    }

    // x-part: ifgo + mk, K=16 this quarter (conflict-free frag layout)
    int ax0, ax1, ax2, ax3, amk;
    {
      const uint4 xw0 = ((const uint4*)XwL)[(0 * 256 + j) * 4 + q];
      const uint4 xw1 = ((const uint4*)XwL)[(1 * 256 + j) * 4 + q];
      const uint4 xw2 = ((const uint4*)XwL)[(2 * 256 + j) * 4 + q];
      const uint4 xw3 = ((const uint4*)XwL)[(3 * 256 + j) * 4 + q];
      const uint4 xwm = ((const uint4*)XwL)[4096 + j * 4 + q];
      ax0 = dot4(xw0.x, X0.x, 0);   ax0 = dot4(xw0.y, X0.y, ax0);
      ax0 = dot4(xw0.z, X0.z, ax0); ax0 = dot4(xw0.w, X0.w, ax0);
      ax1 = dot4(xw1.x, X0.x, 0);   ax1 = dot4(xw1.y, X0.y, ax1);
      ax1 = dot4(xw1.z, X0.z, ax1); ax1 = dot4(xw1.w, X0.w, ax1);
      ax2 = dot4(xw2.x, X0.x, 0);   ax2 = dot4(xw2.y, X0.y, ax2);
      ax2 = dot4(xw2.z, X0.z, ax2); ax2 = dot4(xw2.w, X0.w, ax2);
      ax3 = dot4(xw3.x, X0.x, 0);   ax3 = dot4(xw3.y, X0.y, ax3);
      ax3 = dot4(xw3.z, X0.z, ax3); ax3 = dot4(xw3.w, X0.w, ax3);
      amk = dot4(xwm.x, X0.x, 0);   amk = dot4(xwm.y, X0.y, amk);
      amk = dot4(xwm.z, X0.z, amk); amk = dot4(xwm.w, X0.w, amk);
    }
    // e-part: K=8 this quarter
    const uint2 ew = ((const uint2*)EwL)[j * 4 + q];
    int ae = dot4(ew.x, E0.x, 0);
    ae = dot4(ew.y, E0.y, ae);

    // dequant to per-quarter float partials, reduce across the lane quad
    const float fx = sXF * sv.x;
    float p0 = (float)a0 * kHH + (float)ax0 * fx;
    float p1 = (float)a1 * kHH + (float)ax1 * fx;
    float p2 = (float)a2 * kHH + (float)ax2 * fx;
    float p3 = (float)a3 * kHH + (float)ax3 * fx;
    float p4 = (float)a4 * kHG;
    float p5 = (float)amk * (sMK * sv.x);
    float p6 = (float)ae * (sE * sv.y);
    p0 += __shfl_xor(p0, 1); p0 += __shfl_xor(p0, 2);
    p1 += __shfl_xor(p1, 1); p1 += __shfl_xor(p1, 2);
    p2 += __shfl_xor(p2, 1); p2 += __shfl_xor(p2, 2);
    p3 += __shfl_xor(p3, 1); p3 += __shfl_xor(p3, 2);
    p4 += __shfl_xor(p4, 1); p4 += __shfl_xor(p4, 2);
    p5 += __shfl_xor(p5, 1); p5 += __shfl_xor(p5, 2);
    p6 += __shfl_xor(p6, 1); p6 += __shfl_xor(p6, 2);
    p0 += bf0; p1 += bf1; p2 += bf2; p3 += bf3;
    p4 += bhgv; p5 += bmkv; p6 += bev;

    // elementwise (redundant across the quad; keeps all lanes' c in sync)
    const float impact = tanh_f(p6) * sigm(p4) * sv.z;
    c = sigm(p1) * c + sigm(p0) * tanh_f(p2) + sigm(p5) * tanh_f(impact);
    const float hn = sigm(p3) * tanh_f(c);

    if (q == 0) {
      feat[(size_t)bt * HH + j] = hn;
      int qi = __float2int_rn(hn * 127.0f);  // |h|<1 -> fixed scale 1/127
      hqB[(buf ^ 1) * 256 + j] = (uchar)(qi & 0xff);
    }
    __syncthreads();  // hq[buf^1] ready; hq[buf] reads done
    buf ^= 1;
  }
}

// ---------- predictor: 4 waves cooperate per row-pair; Wp1 bf16 resident in LDS ----------
__global__ __launch_bounds__(256) void pred_f32(
    const float* __restrict__ feat, const uint* __restrict__ WQ,
    const float* __restrict__ bp1, const float* __restrict__ Wp2,
    const float* __restrict__ bp2, float* __restrict__ out0) {
  __shared__ uint WL[128 * 130];        // 66.6 KB, padded stride
  __shared__ float hr[2][2][264];       // [buf][row][k] f32, 8.4 KB

  const int tid = threadIdx.x, w = tid >> 6, l = tid & 63;
  const int j = w * 32 + (l >> 1), kh = l & 1;

  for (int i = tid; i < 16384; i += 256) WL[(i >> 7) * 130 + (i & 127)] = WQ[i];
  const float b1 = bp1[j], w2v = Wp2[j], b2 = bp2[0];
  const int rbase = blockIdx.x * 64;

  if (w == 0) {
    float4 a = ((const float4*)feat)[(size_t)rbase * 64 + l];
    float4 b = ((const float4*)feat)[(size_t)(rbase + 1) * 64 + l];
    ((float4*)&hr[0][0][0])[l] = a;
    ((float4*)&hr[0][1][0])[l] = b;
  }
  __syncthreads();

  const uint* wp = &WL[j * 130 + kh * 64];
  int cb = 0;
  for (int batch = 0; batch < 32; ++batch) {
    float4 na, nb;
    if (w == 0 && batch < 31) {
      na = ((const float4*)feat)[(size_t)(rbase + (batch + 1) * 2) * 64 + l];
      nb = ((const float4*)feat)[(size_t)(rbase + (batch + 1) * 2 + 1) * 64 + l];
    }
    const float* hA = &hr[cb][0][kh * 128];
    const float* hB = &hr[cb][1][kh * 128];
    float midA = 0.f, midB = 0.f;
#pragma unroll 8
    for (int kp = 0; kp < 64; ++kp) {
      const uint wu = wp[kp];
      const float2 ha = *(const float2*)&hA[2 * kp];
      const float2 hb = *(const float2*)&hB[2 * kp];
      const float wlo = blo(wu), whi = bhi(wu);
      midA = fmaf(ha.y, whi, fmaf(ha.x, wlo, midA));
      midB = fmaf(hb.y, whi, fmaf(hb.x, wlo, midB));
    }
    midA += __shfl_xor(midA, 1);
    midB += __shfl_xor(midB, 1);
    float pa = 0.f, pb = 0.f;
    if (kh == 0) {
      const float mA = midA + b1, mB = midB + b1;
      pa = 0.5f * mA * (1.0f + erff(mA * 0.70710678118f)) * w2v;
      pb = 0.5f * mB * (1.0f + erff(mB * 0.70710678118f)) * w2v;
    }
#pragma unroll
    for (int d = 1; d < 64; d <<= 1) { pa += __shfl_xor(pa, d); pb += __shfl_xor(pb, d); }
    if (l == 0) {
      atomicAdd(&out0[rbase + batch * 2], pa + (w == 0 ? b2 : 0.f));
      atomicAdd(&out0[rbase + batch * 2 + 1], pb + (w == 0 ? b2 : 0.f));
    }
    if (w == 0 && batch < 31) {
      ((float4*)&hr[cb ^ 1][0][0])[l] = na;
      ((float4*)&hr[cb ^ 1][1][0])[l] = nb;
    }
    __syncthreads();
    cb ^= 1;
  }
}

extern "C" void kernel_launch(void* const* d_in, const int* in_sizes, int n_in,
                              void* d_out, int out_size, void* d_ws, size_t ws_size,
                              hipStream_t stream) {
  const float* x = (const float*)d_in[0];
  const float* ev = (const float*)d_in[1];
  const float* td = (const float*)d_in[2];
  const float* Wproj = (const float*)d_in[3];
  const float* bproj = (const float*)d_in[4];
  const float* Wih = (const float*)d_in[5];
  const float* Whh = (const float*)d_in[6];
  const float* blstm = (const float*)d_in[7];
  const float* Wmk = (const float*)d_in[8];
  const float* bmk = (const float*)d_in[9];
  const float* We = (const float*)d_in[10];
  const float* be = (const float*)d_in[11];
  const float* Whg = (const float*)d_in[12];
  const float* bhg = (const float*)d_in[13];
  const float* decay = (const float*)d_in[14];
  const float* Wp1 = (const float*)d_in[15];
  const float* bp1 = (const float*)d_in[16];
  const float* Wp2 = (const float*)d_in[17];
  const float* bp2 = (const float*)d_in[18];

  float* out0 = (float*)d_out;                // predictions [B,T,1]
  float* out1 = out0 + (size_t)BT;            // features    [B,T,H]
  float* out2 = out1 + (size_t)BT * HH;       // tmdo d1     [B,T,64]

  char* w = (char*)d_ws;
  float* Wfold_f = (float*)w; w += (size_t)65536 * 4;   // 256 KB
  uint* WhQ = (uint*)w; w += (size_t)81920 * 4;         // 320 KB
  uint* XQ = (uint*)w; w += (size_t)20480 * 4;          // 80 KB
  uint* EQ = (uint*)w; w += (size_t)2048 * 4;           // 8 KB
  uint* WQp = (uint*)w; w += (size_t)16384 * 4;         // 64 KB
  float* scales = (float*)w; w += 16 * 4;
  float* bfold = (float*)w; w += 1024 * 4;
  uint* xq = (uint*)w; w += (size_t)BT * 16 * 4;        // 8 MB
  uint* eq = (uint*)w; w += (size_t)BT * 8 * 4;         // 4 MB
  float4* scl = (float4*)w; w += (size_t)BT * 16;       // 2 MB

  hipMemsetAsync(out0, 0, (size_t)BT * sizeof(float), stream);  // pred accumulates via atomics

  hipLaunchKernelGGL(fold_f32, dim3(256), dim3(256), 0, stream, Wproj, Wih, Wfold_f);
  hipLaunchKernelGGL(bfold_kernel, dim3(4), dim3(256), 0, stream, bproj, Wih, blstm, bfold);
  hipLaunchKernelGGL(quant_all, dim3(5), dim3(1024), 0, stream,
                     Whh, Whg, Wfold_f, Wmk, We, WhQ, XQ, EQ, scales);
  hipLaunchKernelGGL(pack_wp1, dim3(64), dim3(256), 0, stream, Wp1, WQp);
  hipLaunchKernelGGL(prep_inputs, dim3(BT / 4), dim3(256), 0, stream,
                     x, ev, td, decay, xq, eq, scl);
  hipLaunchKernelGGL(d1_kernel, dim3(8192), dim3(256), 0, stream, x, out2);

  hipLaunchKernelGGL(scan_i8, dim3(BB), dim3(1024), 0, stream,
                     WhQ, XQ, EQ, scales, bfold, bhg, bmk, be, xq, eq, scl, out1);

  hipLaunchKernelGGL(pred_f32, dim3(2048), dim3(256), 0, stream,
                     out1, WQp, bp1, Wp2, bp2, out0);
}

// Round 5
// 2626.042 us; speedup vs baseline: 1.0173x; 1.0173x over previous
//
#include <hip/hip_runtime.h>
#include <hip/hip_bf16.h>
#include <math.h>

#define BB 128
#define TT 1024
#define DIN 64
#define HH 256
#define EE 32
#define BT (BB * TT)

typedef unsigned int uint;
typedef unsigned char uchar;

__device__ __forceinline__ int dot4(uint a, uint b, int c) {
  return __builtin_amdgcn_sdot4((int)a, (int)b, c, false);
}
__device__ __forceinline__ unsigned bf16rne(float f) {
  unsigned u = __float_as_uint(f);
  return (u + 0x7fffu + ((u >> 16) & 1u)) >> 16;
}
__device__ __forceinline__ unsigned packbf(float a, float b) {
  return bf16rne(a) | (bf16rne(b) << 16);
}
__device__ __forceinline__ float blo(uint u) { return __uint_as_float(u << 16); }
__device__ __forceinline__ float bhi(uint u) { return __uint_as_float(u & 0xffff0000u); }
__device__ __forceinline__ float rcp_f(float x) { return __builtin_amdgcn_rcpf(x); }
__device__ __forceinline__ float sigm(float x) { return rcp_f(1.0f + __expf(-x)); }
__device__ __forceinline__ float tanh_f(float x) {
  return 1.0f - 2.0f * rcp_f(__expf(2.0f * x) + 1.0f);
}

// ---------- Wfold = W_proj @ W_ih (fp32) ----------
__global__ void fold_f32(const float* __restrict__ Wproj, const float* __restrict__ Wih,
                         float* __restrict__ Wfold) {
  int idx = blockIdx.x * blockDim.x + threadIdx.x;
  if (idx >= 64 * 1024) return;
  int d = idx >> 10, n = idx & 1023;
  float a = 0.f;
  for (int k = 0; k < 256; ++k) a += Wproj[d * 256 + k] * Wih[k * 1024 + n];
  Wfold[d * 1024 + n] = a;
}

// bfold[n] = b_proj @ W_ih + b_lstm
__global__ void bfold_kernel(const float* __restrict__ bproj, const float* __restrict__ Wih,
                             const float* __restrict__ blstm, float* __restrict__ bfold) {
  int n = blockIdx.x * blockDim.x + threadIdx.x;
  if (n >= 1024) return;
  float a = blstm[n];
  for (int k = 0; k < 256; ++k) a += bproj[k] * Wih[k * 1024 + n];
  bfold[n] = a;
}

// ---------- quantize all weight matrices with per-matrix (uniform) scales ----------
// WhV (ifgo of Whh, VGPR-resident in scan): uint idx ((g*256+j)*4+q)*16 + m*4 + mm,
//   covering rows k = q*64 + m*16 + mm*4 + {0..3}, col g*256+j.
// WhL (Whg, LDS-resident in scan): uint idx (m*1024 + (j*4+q))*4 + mm (lane-linear reads).
// XQ: uint idx c*16 + q*4 + mm (c<1024 Wfold col, else Wmk col), k = q*16+mm*4+{0..3}.
// EQ: uint idx c*8 + q*2 + mm, k = q*8 + mm*4 + {0..3}.
__global__ __launch_bounds__(1024) void quant_all(
    const float* __restrict__ Whh, const float* __restrict__ Whg,
    const float* __restrict__ Wfold, const float* __restrict__ Wmk,
    const float* __restrict__ We,
    uint* __restrict__ WhV, uint* __restrict__ WhL,
    uint* __restrict__ XQ, uint* __restrict__ EQ,
    float* __restrict__ scales) {
  const int bid = blockIdx.x, tid = threadIdx.x;
  const float* src;
  int nelem;
  switch (bid) {
    case 0: src = Whh;   nelem = 262144; break;
    case 1: src = Whg;   nelem = 65536;  break;
    case 2: src = Wfold; nelem = 65536;  break;
    case 3: src = Wmk;   nelem = 16384;  break;
    default: src = We;   nelem = 8192;   break;
  }
  float m = 0.f;
  for (int i = tid; i < nelem; i += 1024) m = fmaxf(m, fabsf(src[i]));
#pragma unroll
  for (int d = 1; d < 64; d <<= 1) m = fmaxf(m, __shfl_xor(m, d));
  __shared__ float wm[16];
  if ((tid & 63) == 0) wm[tid >> 6] = m;
  __syncthreads();
  float mg = wm[0];
#pragma unroll
  for (int i = 1; i < 16; ++i) mg = fmaxf(mg, wm[i]);
  mg = fmaxf(mg, 1e-8f);
  if (tid == 0) scales[bid] = mg * (1.0f / 127.0f);
  const float inv = 127.0f / mg;

  if (bid == 0) {  // Whh [256][1024] -> WhV (all 4 gates, frag layout)
    for (int i = tid; i < 65536; i += 1024) {
      int C = i >> 4, r = i & 15;
      int c = C >> 2, q = C & 3, mI = r >> 2, mm = r & 3;
      int k4 = q * 16 + mI * 4 + mm;
      uint d = 0;
#pragma unroll
      for (int bb = 0; bb < 4; ++bb) {
        int qv = __float2int_rn(Whh[(4 * k4 + bb) * 1024 + c] * inv);
        qv = max(-127, min(127, qv));
        d |= ((uint)(qv & 0xff)) << (8 * bb);
      }
      WhV[i] = d;
    }
  } else if (bid == 1) {  // Whg [256][256] -> WhL lane-linear: (m*1024+jq)*4+mm
    for (int i = tid; i < 16384; i += 1024) {
      int mm = i & 3, rest = i >> 2;
      int mI = rest >> 10, jq = rest & 1023;
      int j = jq >> 2, qq = jq & 3;
      int k4 = qq * 16 + mI * 4 + mm;
      uint d = 0;
#pragma unroll
      for (int bb = 0; bb < 4; ++bb) {
        int qv = __float2int_rn(Whg[(4 * k4 + bb) * 256 + j] * inv);
        qv = max(-127, min(127, qv));
        d |= ((uint)(qv & 0xff)) << (8 * bb);
      }
      WhL[i] = d;
    }
  } else if (bid == 2) {  // Wfold [64][1024] -> XQ[0..16384)
    for (int i = tid; i < 16384; i += 1024) {
      int c = i >> 4, r = i & 15;
      int q = r >> 2, mm = r & 3;
      int k4 = q * 4 + mm;
      uint d = 0;
#pragma unroll
      for (int bb = 0; bb < 4; ++bb) {
        int qv = __float2int_rn(Wfold[(4 * k4 + bb) * 1024 + c] * inv);
        qv = max(-127, min(127, qv));
        d |= ((uint)(qv & 0xff)) << (8 * bb);
      }
      XQ[i] = d;
    }
  } else if (bid == 3) {  // Wmk [64][256] -> XQ[16384..20480)
    for (int i = tid; i < 4096; i += 1024) {
      int j = i >> 4, r = i & 15;
      int q = r >> 2, mm = r & 3;
      int k4 = q * 4 + mm;
      uint d = 0;
#pragma unroll
      for (int bb = 0; bb < 4; ++bb) {
        int qv = __float2int_rn(Wmk[(4 * k4 + bb) * 256 + j] * inv);
        qv = max(-127, min(127, qv));
        d |= ((uint)(qv & 0xff)) << (8 * bb);
      }
      XQ[16384 + i] = d;
    }
  } else {  // We [32][256] -> EQ[0..2048)
    for (int i = tid; i < 2048; i += 1024) {
      int c = i >> 3, r = i & 7;
      int q = r >> 1, mm = r & 1;
      int k4 = q * 2 + mm;
      uint d = 0;
#pragma unroll
      for (int bb = 0; bb < 4; ++bb) {
        int qv = __float2int_rn(We[(4 * k4 + bb) * 256 + c] * inv);
        qv = max(-127, min(127, qv));
        d |= ((uint)(qv & 0xff)) << (8 * bb);
      }
      EQ[i] = d;
    }
  }
}

// ---------- pack Wp1 [256][128] -> bf16 k-pairs: WQ[j*128 + kp] ----------
__global__ void pack_wp1(const float* __restrict__ Wp1, uint* __restrict__ WQ) {
  int idx = blockIdx.x * blockDim.x + threadIdx.x;
  if (idx >= 16384) return;
  int j = idx >> 7, kp = idx & 127;
  WQ[idx] = packbf(Wp1[(2 * kp) * 128 + j], Wp1[(2 * kp + 1) * 128 + j]);
}

// ---------- per-(b,t) input quantization + scl={xsc,esc,fac,0} ----------
__global__ __launch_bounds__(256) void prep_inputs(
    const float* __restrict__ x, const float* __restrict__ ev, const float* __restrict__ td,
    const float* __restrict__ decay, uint* __restrict__ xq, uint* __restrict__ eq,
    float4* __restrict__ scl) {
  int wid = threadIdx.x >> 6, lane = threadIdx.x & 63;
  int bt = blockIdx.x * 4 + wid;
  if (bt >= BT) return;
  float xv = x[(size_t)bt * DIN + lane];
  float evv = (lane < EE) ? ev[(size_t)bt * EE + lane] : 0.0f;
  float ax = fabsf(xv), ae = fabsf(evv);
#pragma unroll
  for (int m = 1; m < 64; m <<= 1) {
    ax = fmaxf(ax, __shfl_xor(ax, m));
    ae = fmaxf(ae, __shfl_xor(ae, m));
  }
  float mgx = fmaxf(ax, 1e-8f), mge = fmaxf(ae, 1e-8f);
  int qx = __float2int_rn(xv * (127.0f / mgx));
  qx = max(-127, min(127, qx));
  int qe = __float2int_rn(evv * (127.0f / mge));
  qe = max(-127, min(127, qe));
  uint dx = 0, de = 0;
#pragma unroll
  for (int b = 0; b < 4; ++b) dx |= ((uint)(__shfl(qx, lane * 4 + b) & 0xff)) << (8 * b);
#pragma unroll
  for (int b = 0; b < 4; ++b) de |= ((uint)(__shfl(qe, lane * 4 + b) & 0xff)) << (8 * b);
  if (lane < 16) xq[(size_t)bt * 16 + lane] = dx;
  if (lane < 8) eq[(size_t)bt * 8 + lane] = de;
  if (lane == 0) {
    float sp = log1pf(__expf(decay[0]));
    scl[bt] = make_float4(mgx * (1.0f / 127.0f), mge * (1.0f / 127.0f),
                          __expf(-sp * td[bt]), 0.0f);
  }
}

// ---------- output 2: first temporal difference ----------
__global__ void d1_kernel(const float* __restrict__ x, float* __restrict__ out2) {
  int idx = blockIdx.x * blockDim.x + threadIdx.x;
  const int per_t = DIN / 4;
  if (idx >= BB * TT * per_t) return;
  int t = (idx / per_t) % TT;
  float4 cur = reinterpret_cast<const float4*>(x)[idx];
  float4 res;
  if (t == 0) {
    res = make_float4(0.f, 0.f, 0.f, 0.f);
  } else {
    float4 prv = reinterpret_cast<const float4*>(x)[idx - per_t];
    res = make_float4(cur.x - prv.x, cur.y - prv.y, cur.z - prv.z, cur.w - prv.w);
  }
  reinterpret_cast<float4*>(out2)[idx] = res;
}

// ---------- the scan: 1 block/row, 1024 threads; lane quad (j, q=0..3) splits K ----------
// ifgo h-weights in VGPR (64 regs); hg h-weights + all x/e weights in LDS.
__global__ __launch_bounds__(1024) void scan_i8(
    const uint* __restrict__ WhV, const uint* __restrict__ WhLg,
    const uint* __restrict__ XQ, const uint* __restrict__ EQ,
    const float* __restrict__ scales, const float* __restrict__ bfold,
    const float* __restrict__ bhg, const float* __restrict__ bmk, const float* __restrict__ be,
    const uint* __restrict__ xq, const uint* __restrict__ eqp,
    const float4* __restrict__ scl, float* __restrict__ feat) {
  __shared__ __align__(16) uint XL[20480];  // 80 KB: ifgo-x + mk
  __shared__ __align__(16) uint WL[16384];  // 64 KB: hg (lane-linear frags)
  __shared__ __align__(16) uint EL[2048];   //  8 KB
  __shared__ __align__(16) uint hqW[128];   // 512 B double-buffered int8 h

  const int tid = threadIdx.x, b = blockIdx.x;
  const int j = tid >> 2, q = tid & 3;
  uchar* hqB = (uchar*)hqW;

  for (int i = tid; i < 5120; i += 1024) ((uint4*)XL)[i] = ((const uint4*)XQ)[i];
  for (int i = tid; i < 4096; i += 1024) ((uint4*)WL)[i] = ((const uint4*)WhLg)[i];
  for (int i = tid; i < 2048; i += 1024) EL[i] = EQ[i];
  if (tid < 64) hqW[tid] = 0;  // h(0) = 0 in buffer 0

  // ifgo h-weights, this thread's K-quarter: 4 x 4 uint4 = 64 VGPRs
  uint4 wh[4][4];
  const uint4* wv = (const uint4*)WhV;
#pragma unroll
  for (int g = 0; g < 4; ++g)
#pragma unroll
    for (int m = 0; m < 4; ++m) wh[g][m] = wv[(g * 1024 + tid) * 4 + m];

  const float kHH = scales[0] * (1.0f / 127.0f);
  const float kHG = scales[1] * (1.0f / 127.0f);
  const float sXF = scales[2], sMK = scales[3], sE = scales[4];

  const float bf0 = bfold[j], bf1 = bfold[256 + j], bf2 = bfold[512 + j], bf3 = bfold[768 + j];
  const float bhgv = bhg[j], bmkv = bmk[j], bev = be[j];

  float c = 0.0f;
  int buf = 0;
  const uint4* xq4 = (const uint4*)xq + (size_t)b * TT * 4;
  const uint2* eq2 = (const uint2*)eqp + (size_t)b * TT * 4;
  const float4* svp = scl + (size_t)b * TT;
  float* fout = feat + (size_t)b * TT * HH;
  const uint4* XL4 = (const uint4*)XL;
  const uint4* WL4 = (const uint4*)WL;
  const uint2* EL2 = (const uint2*)EL;
  __syncthreads();

#pragma unroll 1
  for (int t = 0; t < TT; ++t) {
    // per-step inputs (issued early, consumed later)
    const uint4 X0 = xq4[t * 4 + q];
    const uint2 E0 = eq2[t * 4 + q];
    const float4 sv = svp[t];

    // x-part: ifgo + mk (K=16 this quarter), e (K=8 this quarter)
    const uint4 xw0 = XL4[0 * 1024 + tid];
    const uint4 xw1 = XL4[1 * 1024 + tid];
    const uint4 xw2 = XL4[2 * 1024 + tid];
    const uint4 xw3 = XL4[3 * 1024 + tid];
    const uint4 xwm = XL4[4 * 1024 + tid];
    const uint2 ew = EL2[tid];
    int ax0 = dot4(xw0.x, X0.x, 0);   ax0 = dot4(xw0.y, X0.y, ax0);
    ax0 = dot4(xw0.z, X0.z, ax0);     ax0 = dot4(xw0.w, X0.w, ax0);
    int ax1 = dot4(xw1.x, X0.x, 0);   ax1 = dot4(xw1.y, X0.y, ax1);
    ax1 = dot4(xw1.z, X0.z, ax1);     ax1 = dot4(xw1.w, X0.w, ax1);
    int ax2 = dot4(xw2.x, X0.x, 0);   ax2 = dot4(xw2.y, X0.y, ax2);
    ax2 = dot4(xw2.z, X0.z, ax2);     ax2 = dot4(xw2.w, X0.w, ax2);
    int ax3 = dot4(xw3.x, X0.x, 0);   ax3 = dot4(xw3.y, X0.y, ax3);
    ax3 = dot4(xw3.z, X0.z, ax3);     ax3 = dot4(xw3.w, X0.w, ax3);
    int amk = dot4(xwm.x, X0.x, 0);   amk = dot4(xwm.y, X0.y, amk);
    amk = dot4(xwm.z, X0.z, amk);     amk = dot4(xwm.w, X0.w, amk);
    int ae = dot4(ew.x, E0.x, 0);     ae = dot4(ew.y, E0.y, ae);

    // h-part: ifgo from VGPR weights, hg from LDS (K=64 this quarter)
    int a0 = 0, a1 = 0, a2 = 0, a3 = 0, a4 = 0;
    const uint4* hp = (const uint4*)(hqB + buf * 256 + q * 64);
#pragma unroll
    for (int m = 0; m < 4; ++m) {
      const uint4 hv = hp[m];
      const uint4 wg = WL4[m * 1024 + tid];
      a0 = dot4(wh[0][m].x, hv.x, a0); a0 = dot4(wh[0][m].y, hv.y, a0);
      a0 = dot4(wh[0][m].z, hv.z, a0); a0 = dot4(wh[0][m].w, hv.w, a0);
      a1 = dot4(wh[1][m].x, hv.x, a1); a1 = dot4(wh[1][m].y, hv.y, a1);
      a1 = dot4(wh[1][m].z, hv.z, a1); a1 = dot4(wh[1][m].w, hv.w, a1);
      a2 = dot4(wh[2][m].x, hv.x, a2); a2 = dot4(wh[2][m].y, hv.y, a2);
      a2 = dot4(wh[2][m].z, hv.z, a2); a2 = dot4(wh[2][m].w, hv.w, a2);
      a3 = dot4(wh[3][m].x, hv.x, a3); a3 = dot4(wh[3][m].y, hv.y, a3);
      a3 = dot4(wh[3][m].z, hv.z, a3); a3 = dot4(wh[3][m].w, hv.w, a3);
      a4 = dot4(wg.x, hv.x, a4);       a4 = dot4(wg.y, hv.y, a4);
      a4 = dot4(wg.z, hv.z, a4);       a4 = dot4(wg.w, hv.w, a4);
    }

    // dequant + combine, reduce across the lane quad
    const float fx = sXF * sv.x;
    float p0 = (float)a0 * kHH + (float)ax0 * fx;
    float p1 = (float)a1 * kHH + (float)ax1 * fx;
    float p2 = (float)a2 * kHH + (float)ax2 * fx;
    float p3 = (float)a3 * kHH + (float)ax3 * fx;
    float p4 = (float)a4 * kHG;
    float p5 = (float)amk * (sMK * sv.x);
    float p6 = (float)ae * (sE * sv.y);
    p0 += __shfl_xor(p0, 1); p0 += __shfl_xor(p0, 2);
    p1 += __shfl_xor(p1, 1); p1 += __shfl_xor(p1, 2);
    p2 += __shfl_xor(p2, 1); p2 += __shfl_xor(p2, 2);
    p3 += __shfl_xor(p3, 1); p3 += __shfl_xor(p3, 2);
    p4 += __shfl_xor(p4, 1); p4 += __shfl_xor(p4, 2);
    p5 += __shfl_xor(p5, 1); p5 += __shfl_xor(p5, 2);
    p6 += __shfl_xor(p6, 1); p6 += __shfl_xor(p6, 2);
    p0 += bf0; p1 += bf1; p2 += bf2; p3 += bf3;
    p4 += bhgv; p5 += bmkv; p6 += bev;

    // elementwise (redundant across the quad)
    const float impact = tanh_f(p6) * sigm(p4) * sv.z;
    c = sigm(p1) * c + sigm(p0) * tanh_f(p2) + sigm(p5) * tanh_f(impact);
    const float hn = sigm(p3) * tanh_f(c);

    if (q == 0) {
      fout[t * HH + j] = hn;
      int qi = __float2int_rn(hn * 127.0f);  // |h|<1 -> fixed scale 1/127
      hqB[(buf ^ 1) * 256 + j] = (uchar)(qi & 0xff);
    }
    __syncthreads();  // hq[buf^1] ready; hq[buf] reads done
    buf ^= 1;
  }
}

// ---------- predictor: 64-row x 128-col tile per block, bf16 W + h in LDS ----------
__global__ __launch_bounds__(256) void pred_f32(
    const float* __restrict__ feat, const uint* __restrict__ WQ,
    const float* __restrict__ bp1, const float* __restrict__ Wp2,
    const float* __restrict__ bp2, float* __restrict__ out0) {
  __shared__ uint hT[64 * 130];   // [row][kp] bf16 pairs, padded stride (33.3 KB)
  __shared__ uint WL[16384];      // [j][kp] bf16 pairs (64 KB)
  __shared__ float wp2s[128];
  __shared__ float bp1s[128];
  __shared__ float psum[4][64];

  const int tid = threadIdx.x, w = tid >> 6, l = tid & 63;
  const int rbase = blockIdx.x * 64;

  for (int i = tid; i < 16384; i += 256) WL[i] = WQ[i];
  if (tid < 128) { wp2s[tid] = Wp2[tid]; bp1s[tid] = bp1[tid]; }
  for (int i = tid; i < 8192; i += 256) {
    int row = i >> 7, kp = i & 127;
    const float2 hv = ((const float2*)feat)[(size_t)(rbase + row) * 128 + kp];
    hT[row * 130 + kp] = packbf(hv.x, hv.y);
  }
  __syncthreads();

  // wave w owns j-block [w*32, w*32+32); lane l owns row l
  float mid[32];
#pragma unroll
  for (int jj = 0; jj < 32; ++jj) mid[jj] = 0.f;
  const uint* hrow = &hT[l * 130];
  const uint* wbase = &WL[(w * 32) * 128];
  for (int kp = 0; kp < 128; ++kp) {
    const uint hu = hrow[kp];
    const float h0 = blo(hu), h1 = bhi(hu);
#pragma unroll
    for (int jj = 0; jj < 32; ++jj) {
      const uint wu = wbase[jj * 128 + kp];  // wave-uniform broadcast read
      mid[jj] = fmaf(h1, bhi(wu), fmaf(h0, blo(wu), mid[jj]));
    }
  }
  float acc = 0.f;
#pragma unroll
  for (int jj = 0; jj < 32; ++jj) {
    const float m = mid[jj] + bp1s[w * 32 + jj];
    acc += 0.5f * m * (1.0f + erff(m * 0.70710678118f)) * wp2s[w * 32 + jj];
  }
  psum[w][l] = acc;
  __syncthreads();
  if (w == 0)
    out0[rbase + l] = psum[0][l] + psum[1][l] + psum[2][l] + psum[3][l] + bp2[0];
}

extern "C" void kernel_launch(void* const* d_in, const int* in_sizes, int n_in,
                              void* d_out, int out_size, void* d_ws, size_t ws_size,
                              hipStream_t stream) {
  const float* x = (const float*)d_in[0];
  const float* ev = (const float*)d_in[1];
  const float* td = (const float*)d_in[2];
  const float* Wproj = (const float*)d_in[3];
  const float* bproj = (const float*)d_in[4];
  const float* Wih = (const float*)d_in[5];
  const float* Whh = (const float*)d_in[6];
  const float* blstm = (const float*)d_in[7];
  const float* Wmk = (const float*)d_in[8];
  const float* bmk = (const float*)d_in[9];
  const float* We = (const float*)d_in[10];
  const float* be = (const float*)d_in[11];
  const float* Whg = (const float*)d_in[12];
  const float* bhg = (const float*)d_in[13];
  const float* decay = (const float*)d_in[14];
  const float* Wp1 = (const float*)d_in[15];
  const float* bp1 = (const float*)d_in[16];
  const float* Wp2 = (const float*)d_in[17];
  const float* bp2 = (const float*)d_in[18];

  float* out0 = (float*)d_out;                // predictions [B,T,1]
  float* out1 = out0 + (size_t)BT;            // features    [B,T,H]
  float* out2 = out1 + (size_t)BT * HH;       // tmdo d1     [B,T,64]

  char* w = (char*)d_ws;
  float* Wfold_f = (float*)w; w += (size_t)65536 * 4;   // 256 KB
  uint* WhV = (uint*)w; w += (size_t)65536 * 4;         // 256 KB
  uint* WhL = (uint*)w; w += (size_t)16384 * 4;         // 64 KB
  uint* XQ = (uint*)w; w += (size_t)20480 * 4;          // 80 KB
  uint* EQ = (uint*)w; w += (size_t)2048 * 4;           // 8 KB
  uint* WQp = (uint*)w; w += (size_t)16384 * 4;         // 64 KB
  float* scales = (float*)w; w += 16 * 4;
  float* bfold = (float*)w; w += 1024 * 4;
  uint* xq = (uint*)w; w += (size_t)BT * 16 * 4;        // 8 MB
  uint* eq = (uint*)w; w += (size_t)BT * 8 * 4;         // 4 MB
  float4* scl = (float4*)w; w += (size_t)BT * 16;       // 2 MB

  hipLaunchKernelGGL(fold_f32, dim3(256), dim3(256), 0, stream, Wproj, Wih, Wfold_f);
  hipLaunchKernelGGL(bfold_kernel, dim3(4), dim3(256), 0, stream, bproj, Wih, blstm, bfold);
  hipLaunchKernelGGL(quant_all, dim3(5), dim3(1024), 0, stream,
                     Whh, Whg, Wfold_f, Wmk, We, WhV, WhL, XQ, EQ, scales);
  hipLaunchKernelGGL(pack_wp1, dim3(64), dim3(256), 0, stream, Wp1, WQp);
  hipLaunchKernelGGL(prep_inputs, dim3(BT / 4), dim3(256), 0, stream,
                     x, ev, td, decay, xq, eq, scl);
  hipLaunchKernelGGL(d1_kernel, dim3(8192), dim3(256), 0, stream, x, out2);

  hipLaunchKernelGGL(scan_i8, dim3(BB), dim3(1024), 0, stream,
                     WhV, WhL, XQ, EQ, scales, bfold, bhg, bmk, be, xq, eq, scl, out1);

  hipLaunchKernelGGL(pred_f32, dim3(BT / 64), dim3(256), 0, stream,
                     out1, WQp, bp1, Wp2, bp2, out0);
}

// Round 7
// 2108.758 us; speedup vs baseline: 1.2669x; 1.2453x over previous
//
#include <hip/hip_runtime.h>
#include <hip/hip_bf16.h>
#include <hip/hip_fp16.h>
#include <math.h>

#define BB 128
#define TT 1024
#define DIN 64
#define HH 256
#define EE 32
#define BT (BB * TT)

typedef unsigned int uint;
typedef unsigned char uchar;
typedef _Float16 half2v __attribute__((ext_vector_type(2)));

__device__ __forceinline__ int dot4(uint a, uint b, int c) {
  return __builtin_amdgcn_sdot4((int)a, (int)b, c, false);
}
__device__ __forceinline__ uint pkh(float a, float b) {
  return __builtin_bit_cast(uint, __builtin_amdgcn_cvt_pkrtz(a, b));
}
__device__ __forceinline__ half2v uph(uint u) { return __builtin_bit_cast(half2v, u); }
__device__ __forceinline__ float fdot2u(uint a, uint b, float c) {
  return __builtin_amdgcn_fdot2(uph(a), uph(b), c, false);
}
#define IDPP(v, c) __builtin_amdgcn_mov_dpp((v), (c), 0xF, 0xF, true)
#define FDPP(v, c) __int_as_float(__builtin_amdgcn_mov_dpp(__float_as_int(v), (c), 0xF, 0xF, true))
__device__ __forceinline__ int qsum(int v) {  // quad butterfly sum (VALU only)
  v += IDPP(v, 0xB1);  // xor 1
  v += IDPP(v, 0x4E);  // xor 2
  return v;
}
__device__ __forceinline__ float rcp_f(float x) { return __builtin_amdgcn_rcpf(x); }
__device__ __forceinline__ float sigm(float x) { return rcp_f(1.0f + __expf(-x)); }
__device__ __forceinline__ float tanh_f(float x) {
  return 1.0f - 2.0f * rcp_f(__expf(2.0f * x) + 1.0f);
}

// ---------- Wfold = W_proj @ W_ih (fp32) ----------
__global__ void fold_f32(const float* __restrict__ Wproj, const float* __restrict__ Wih,
                         float* __restrict__ Wfold) {
  int idx = blockIdx.x * blockDim.x + threadIdx.x;
  if (idx >= 64 * 1024) return;
  int d = idx >> 10, n = idx & 1023;
  float a = 0.f;
  for (int k = 0; k < 256; ++k) a += Wproj[d * 256 + k] * Wih[k * 1024 + n];
  Wfold[d * 1024 + n] = a;
}

// bfold[n] = b_proj @ W_ih + b_lstm
__global__ void bfold_kernel(const float* __restrict__ bproj, const float* __restrict__ Wih,
                             const float* __restrict__ blstm, float* __restrict__ bfold) {
  int n = blockIdx.x * blockDim.x + threadIdx.x;
  if (n >= 1024) return;
  float a = blstm[n];
  for (int k = 0; k < 256; ++k) a += bproj[k] * Wih[k * 1024 + n];
  bfold[n] = a;
}

// ---------- quantize weights, per-matrix scales ----------
__global__ __launch_bounds__(1024) void quant_all(
    const float* __restrict__ Whh, const float* __restrict__ Whg,
    const float* __restrict__ Wfold, const float* __restrict__ Wmk,
    const float* __restrict__ We,
    uint* __restrict__ WhV, uint* __restrict__ WhL,
    uint* __restrict__ XQ, uint* __restrict__ EQ,
    float* __restrict__ scales) {
  const int bid = blockIdx.x, tid = threadIdx.x;
  const float* src;
  int nelem;
  switch (bid) {
    case 0: src = Whh;   nelem = 262144; break;
    case 1: src = Whg;   nelem = 65536;  break;
    case 2: src = Wfold; nelem = 65536;  break;
    case 3: src = Wmk;   nelem = 16384;  break;
    default: src = We;   nelem = 8192;   break;
  }
  float m = 0.f;
  for (int i = tid; i < nelem; i += 1024) m = fmaxf(m, fabsf(src[i]));
#pragma unroll
  for (int d = 1; d < 64; d <<= 1) m = fmaxf(m, __shfl_xor(m, d));
  __shared__ float wm[16];
  if ((tid & 63) == 0) wm[tid >> 6] = m;
  __syncthreads();
  float mg = wm[0];
#pragma unroll
  for (int i = 1; i < 16; ++i) mg = fmaxf(mg, wm[i]);
  mg = fmaxf(mg, 1e-8f);
  if (tid == 0) scales[bid] = mg * (1.0f / 127.0f);
  const float inv = 127.0f / mg;

  if (bid == 0) {  // Whh -> WhV frag layout
    for (int i = tid; i < 65536; i += 1024) {
      int C = i >> 4, r = i & 15;
      int c = C >> 2, q = C & 3, mI = r >> 2, mm = r & 3;
      int k4 = q * 16 + mI * 4 + mm;
      uint d = 0;
#pragma unroll
      for (int bb = 0; bb < 4; ++bb) {
        int qv = __float2int_rn(Whh[(4 * k4 + bb) * 1024 + c] * inv);
        qv = max(-127, min(127, qv));
        d |= ((uint)(qv & 0xff)) << (8 * bb);
      }
      WhV[i] = d;
    }
  } else if (bid == 1) {  // Whg -> WhL lane-linear
    for (int i = tid; i < 16384; i += 1024) {
      int mm = i & 3, rest = i >> 2;
      int mI = rest >> 10, jq = rest & 1023;
      int j = jq >> 2, qq = jq & 3;
      int k4 = qq * 16 + mI * 4 + mm;
      uint d = 0;
#pragma unroll
      for (int bb = 0; bb < 4; ++bb) {
        int qv = __float2int_rn(Whg[(4 * k4 + bb) * 256 + j] * inv);
        qv = max(-127, min(127, qv));
        d |= ((uint)(qv & 0xff)) << (8 * bb);
      }
      WhL[i] = d;
    }
  } else if (bid == 2) {  // Wfold -> XQ col-major (identity k4 order)
    for (int i = tid; i < 16384; i += 1024) {
      int c = i >> 4, k4 = i & 15;
      uint d = 0;
#pragma unroll
      for (int bb = 0; bb < 4; ++bb) {
        int qv = __float2int_rn(Wfold[(4 * k4 + bb) * 1024 + c] * inv);
        qv = max(-127, min(127, qv));
        d |= ((uint)(qv & 0xff)) << (8 * bb);
      }
      XQ[i] = d;
    }
  } else if (bid == 3) {  // Wmk -> XQ[16384..20480)
    for (int i = tid; i < 4096; i += 1024) {
      int j = i >> 4, k4 = i & 15;
      uint d = 0;
#pragma unroll
      for (int bb = 0; bb < 4; ++bb) {
        int qv = __float2int_rn(Wmk[(4 * k4 + bb) * 256 + j] * inv);
        qv = max(-127, min(127, qv));
        d |= ((uint)(qv & 0xff)) << (8 * bb);
      }
      XQ[16384 + i] = d;
    }
  } else {  // We -> EQ col-major
    for (int i = tid; i < 2048; i += 1024) {
      int c = i >> 3, k4 = i & 7;
      uint d = 0;
#pragma unroll
      for (int bb = 0; bb < 4; ++bb) {
        int qv = __float2int_rn(We[(4 * k4 + bb) * 256 + c] * inv);
        qv = max(-127, min(127, qv));
        d |= ((uint)(qv & 0xff)) << (8 * bb);
      }
      EQ[i] = d;
    }
  }
}

// ---------- pack Wp1 [256][128] -> f16 k-pairs: WQ[j*128 + kp] ----------
__global__ void pack_wp1h(const float* __restrict__ Wp1, uint* __restrict__ WQ) {
  int idx = blockIdx.x * blockDim.x + threadIdx.x;
  if (idx >= 16384) return;
  int j = idx >> 7, kp = idx & 127;
  WQ[idx] = pkh(Wp1[(2 * kp) * 128 + j], Wp1[(2 * kp + 1) * 128 + j]);
}

// ---------- per-(b,t) input quantization + scl={xsc,esc,fac,0} ----------
__global__ __launch_bounds__(256) void prep_inputs(
    const float* __restrict__ x, const float* __restrict__ ev, const float* __restrict__ td,
    const float* __restrict__ decay, uint* __restrict__ xq, uint* __restrict__ eq,
    float4* __restrict__ scl) {
  int wid = threadIdx.x >> 6, lane = threadIdx.x & 63;
  int bt = blockIdx.x * 4 + wid;
  if (bt >= BT) return;
  float xv = x[(size_t)bt * DIN + lane];
  float evv = (lane < EE) ? ev[(size_t)bt * EE + lane] : 0.0f;
  float ax = fabsf(xv), ae = fabsf(evv);
#pragma unroll
  for (int m = 1; m < 64; m <<= 1) {
    ax = fmaxf(ax, __shfl_xor(ax, m));
    ae = fmaxf(ae, __shfl_xor(ae, m));
  }
  float mgx = fmaxf(ax, 1e-8f), mge = fmaxf(ae, 1e-8f);
  int qx = __float2int_rn(xv * (127.0f / mgx));
  qx = max(-127, min(127, qx));
  int qe = __float2int_rn(evv * (127.0f / mge));
  qe = max(-127, min(127, qe));
  uint dx = 0, de = 0;
#pragma unroll
  for (int b = 0; b < 4; ++b) dx |= ((uint)(__shfl(qx, lane * 4 + b) & 0xff)) << (8 * b);
#pragma unroll
  for (int b = 0; b < 4; ++b) de |= ((uint)(__shfl(qe, lane * 4 + b) & 0xff)) << (8 * b);
  if (lane < 16) xq[(size_t)bt * 16 + lane] = dx;
  if (lane < 8) eq[(size_t)bt * 8 + lane] = de;
  if (lane == 0) {
    float sp = log1pf(__expf(decay[0]));
    scl[bt] = make_float4(mgx * (1.0f / 127.0f), mge * (1.0f / 127.0f),
                          __expf(-sp * td[bt]), 0.0f);
  }
}

// ---------- output 2: first temporal difference ----------
__global__ void d1_kernel(const float* __restrict__ x, float* __restrict__ out2) {
  int idx = blockIdx.x * blockDim.x + threadIdx.x;
  const int per_t = DIN / 4;
  if (idx >= BB * TT * per_t) return;
  int t = (idx / per_t) % TT;
  float4 cur = reinterpret_cast<const float4*>(x)[idx];
  float4 res;
  if (t == 0) {
    res = make_float4(0.f, 0.f, 0.f, 0.f);
  } else {
    float4 prv = reinterpret_cast<const float4*>(x)[idx - per_t];
    res = make_float4(cur.x - prv.x, cur.y - prv.y, cur.z - prv.z, cur.w - prv.w);
  }
  reinterpret_cast<float4*>(out2)[idx] = res;
}

// ---------- precompute x/e-side per (bt, j): {f16 ifgo preacts+bias, mkS, EF} ----------
// 1024 thr = 256 j x 4 g (quad). idx range covers a T-chunk: idx = b*steps + tloc.
__global__ __launch_bounds__(1024) void pre_kernel(
    int t0, int lsteps,
    const uint* __restrict__ XQ, const uint* __restrict__ EQ,
    const float* __restrict__ scales, const float* __restrict__ bfold,
    const float* __restrict__ bmk, const float* __restrict__ be,
    const uint* __restrict__ xq, const uint* __restrict__ eqp,
    const float4* __restrict__ scl, uint4* __restrict__ pre) {
  const int tid = threadIdx.x;
  const int jj = tid >> 2, g = tid & 3;
  uint wx[16];
#pragma unroll
  for (int k = 0; k < 16; ++k) wx[k] = XQ[(g * 256 + jj) * 16 + k];
  uint wm[4];
#pragma unroll
  for (int k = 0; k < 4; ++k) wm[k] = XQ[16384 + jj * 16 + g * 4 + k];
  const uint we0 = EQ[jj * 8 + g * 2], we1 = EQ[jj * 8 + g * 2 + 1];
  const float sXF = scales[2], sMK = scales[3], sE = scales[4];
  const float bf = bfold[g * 256 + jj];
  const float bmkv = bmk[jj], bev = be[jj];
  const int steps = 1 << lsteps;

  for (int it = 0; it < 64; ++it) {
    const int idx = blockIdx.x * 64 + it;
    const int b = idx >> lsteps, tl = idx & (steps - 1);
    const int bt = b * TT + t0 + tl;
    const uint4* x4 = (const uint4*)(xq + (size_t)bt * 16);
    const uint4 X0 = x4[0], X1 = x4[1], X2 = x4[2], X3 = x4[3];
    const uint4 Xg = x4[g];
    const uint2 E0 = ((const uint2*)(eqp + (size_t)bt * 8))[g];
    const float4 sv = scl[bt];

    int ag = 0;
    ag = dot4(wx[0], X0.x, ag);  ag = dot4(wx[1], X0.y, ag);
    ag = dot4(wx[2], X0.z, ag);  ag = dot4(wx[3], X0.w, ag);
    ag = dot4(wx[4], X1.x, ag);  ag = dot4(wx[5], X1.y, ag);
    ag = dot4(wx[6], X1.z, ag);  ag = dot4(wx[7], X1.w, ag);
    ag = dot4(wx[8], X2.x, ag);  ag = dot4(wx[9], X2.y, ag);
    ag = dot4(wx[10], X2.z, ag); ag = dot4(wx[11], X2.w, ag);
    ag = dot4(wx[12], X3.x, ag); ag = dot4(wx[13], X3.y, ag);
    ag = dot4(wx[14], X3.z, ag); ag = dot4(wx[15], X3.w, ag);

    int am = 0;
    am = dot4(wm[0], Xg.x, am); am = dot4(wm[1], Xg.y, am);
    am = dot4(wm[2], Xg.z, am); am = dot4(wm[3], Xg.w, am);
    int ae = dot4(we0, E0.x, 0);
    ae = dot4(we1, E0.y, ae);
    am = qsum(am);
    ae = qsum(ae);

    const float p = (float)ag * (sXF * sv.x) + bf;
    const float p1 = FDPP(p, 0x55);  // lane1 (f) broadcast
    const float p2 = FDPP(p, 0xAA);  // lane2 (g)
    const float p3 = FDPP(p, 0xFF);  // lane3 (o)
    if (g == 0) {
      const float mkS = sigm((float)am * (sMK * sv.x) + bmkv);
      const float ge = (float)ae * (sE * sv.y) + bev;
      const float EF = tanh_f(ge) * sv.z;
      uint4 o;
      o.x = pkh(p, p1);
      o.y = pkh(p2, p3);
      o.z = __float_as_uint(mkS);
      o.w = __float_as_uint(EF);
      pre[(size_t)idx * 256 + jj] = o;
    }
  }
}

// ---------- the scan: h-side only; 1 block/row, 1024 thr; quad K-split; DPP reduce ----------
__attribute__((amdgpu_waves_per_eu(4, 4)))
__global__ __launch_bounds__(1024) void scan3(
    int t0, int steps,
    const uint* __restrict__ WhV, const uint* __restrict__ WhLg,
    const float* __restrict__ scales, const float* __restrict__ bhg,
    const uint4* __restrict__ pre, uchar* __restrict__ hB, float* __restrict__ cB,
    float* __restrict__ feat) {
  __shared__ __align__(16) uint WL[16384];  // hg weights (64 KB)
  __shared__ __align__(16) uint hqW[128];   // double-buffered int8 h (512 B)
  const int tid = threadIdx.x, b = blockIdx.x;
  const int j = tid >> 2, q = tid & 3;

  for (int i = tid; i < 4096; i += 1024) ((uint4*)WL)[i] = ((const uint4*)WhLg)[i];

  uint4 wh[4][4];  // ifgo h-weights, this K-quarter: 64 VGPRs
  const uint4* wv = (const uint4*)WhV;
#pragma unroll
  for (int g = 0; g < 4; ++g)
#pragma unroll
    for (int m = 0; m < 4; ++m) wh[g][m] = wv[(g * 1024 + tid) * 4 + m];

  float c;
  if (t0 == 0) {
    c = 0.0f;
    if (tid < 64) hqW[tid] = 0u;
  } else {
    c = cB[b * 256 + j];
    if (tid < 64) hqW[tid] = ((const uint*)hB)[b * 64 + tid];
  }
  const float kHH = scales[0] * (1.0f / 127.0f);
  const float kHG = scales[1] * (1.0f / 127.0f);
  const float bhgv = bhg[j];
  const uint4* prep = pre + (size_t)b * steps * 256;
  float* fout = feat + ((size_t)b * TT + t0) * HH;
  const uint4* WL4 = (const uint4*)WL;
  int buf = 0;
  __syncthreads();

  uint4 P = prep[j];  // t=0 preacts
  for (int t = 0; t < steps; ++t) {
    uint4 Pn = P;
    if (t + 1 < steps) Pn = prep[(size_t)(t + 1) * 256 + j];  // prefetch next step

    int a0 = 0, a1 = 0, a2 = 0, a3 = 0, a4 = 0;
    const uint4* hp = (const uint4*)((const uchar*)hqW + buf * 256 + q * 64);
#pragma unroll
    for (int m = 0; m < 4; ++m) {
      const uint4 hv = hp[m];
      const uint4 wg = WL4[m * 1024 + tid];
      a0 = dot4(wh[0][m].x, hv.x, a0); a0 = dot4(wh[0][m].y, hv.y, a0);
      a0 = dot4(wh[0][m].z, hv.z, a0); a0 = dot4(wh[0][m].w, hv.w, a0);
      a1 = dot4(wh[1][m].x, hv.x, a1); a1 = dot4(wh[1][m].y, hv.y, a1);
      a1 = dot4(wh[1][m].z, hv.z, a1); a1 = dot4(wh[1][m].w, hv.w, a1);
      a2 = dot4(wh[2][m].x, hv.x, a2); a2 = dot4(wh[2][m].y, hv.y, a2);
      a2 = dot4(wh[2][m].z, hv.z, a2); a2 = dot4(wh[2][m].w, hv.w, a2);
      a3 = dot4(wh[3][m].x, hv.x, a3); a3 = dot4(wh[3][m].y, hv.y, a3);
      a3 = dot4(wh[3][m].z, hv.z, a3); a3 = dot4(wh[3][m].w, hv.w, a3);
      a4 = dot4(wg.x, hv.x, a4);       a4 = dot4(wg.y, hv.y, a4);
      a4 = dot4(wg.z, hv.z, a4);       a4 = dot4(wg.w, hv.w, a4);
    }
    a0 = qsum(a0); a1 = qsum(a1); a2 = qsum(a2); a3 = qsum(a3); a4 = qsum(a4);

    const half2v pif = uph(P.x), pgo = uph(P.y);
    const float p0 = (float)a0 * kHH + (float)pif.x;
    const float p1 = (float)a1 * kHH + (float)pif.y;
    const float p2 = (float)a2 * kHH + (float)pgo.x;
    const float p3 = (float)a3 * kHH + (float)pgo.y;
    const float p4 = (float)a4 * kHG + bhgv;
    const float mkS = __uint_as_float(P.z);
    const float EF = __uint_as_float(P.w);

    const float impact = EF * sigm(p4);
    c = sigm(p1) * c + sigm(p0) * tanh_f(p2) + mkS * tanh_f(impact);
    const float hn = sigm(p3) * tanh_f(c);

    if (q == 0) {
      fout[(size_t)t * HH + j] = hn;
      int qi = __float2int_rn(hn * 127.0f);
      ((uchar*)hqW)[(buf ^ 1) * 256 + j] = (uchar)(qi & 0xff);
    }
    __syncthreads();
    buf ^= 1;
    P = Pn;
  }
  if (q == 0) cB[b * 256 + j] = c;
  if (tid < 64) ((uint*)hB)[b * 64 + tid] = hqW[buf * 64 + tid];
}

// ---------- predictor: f16 pairs + v_dot2; 128 rows/block; thread=(j, K-half) ----------
__global__ __launch_bounds__(256) void pred3(
    const float* __restrict__ feat, const uint* __restrict__ WQh,
    const float* __restrict__ bp1, const float* __restrict__ Wp2,
    const float* __restrict__ bp2, float* __restrict__ out0) {
  __shared__ uint WL[16384];       // W1 f16-pairs [j][kp] (64 KB)
  __shared__ uint hT[128 * 132];   // h f16-pairs [row][kp], padded stride (67.6 KB)
  __shared__ float psum[4][128];

  const int tid = threadIdx.x, w = tid >> 6, l = tid & 63;
  const int rbase = blockIdx.x * 128;

  for (int i = tid; i < 16384; i += 256) WL[i] = WQh[i];
  for (int i = tid; i < 16384; i += 256) {
    int row = i >> 7, kp = i & 127;
    const float2 hv = ((const float2*)feat)[(size_t)(rbase + row) * 128 + kp];
    hT[row * 132 + kp] = pkh(hv.x, hv.y);
  }
  __syncthreads();

  float ma[32], mb[32];
#pragma unroll
  for (int jj = 0; jj < 32; ++jj) {
    const float bv = bp1[w * 32 + jj];
    ma[jj] = bv;
    mb[jj] = bv;
  }
  const uint* ha = &hT[l * 132];
  const uint* hb = &hT[(l + 64) * 132];
  const uint* wbase = &WL[(w * 32) * 128];
  for (int kp4 = 0; kp4 < 32; ++kp4) {
    const uint4 a4 = *(const uint4*)&ha[kp4 * 4];
    const uint4 b4 = *(const uint4*)&hb[kp4 * 4];
#pragma unroll
    for (int jj = 0; jj < 32; ++jj) {
      const uint4 w4 = *(const uint4*)&wbase[jj * 128 + kp4 * 4];
      ma[jj] = fdot2u(w4.x, a4.x, ma[jj]);
      ma[jj] = fdot2u(w4.y, a4.y, ma[jj]);
      ma[jj] = fdot2u(w4.z, a4.z, ma[jj]);
      ma[jj] = fdot2u(w4.w, a4.w, ma[jj]);
      mb[jj] = fdot2u(w4.x, b4.x, mb[jj]);
      mb[jj] = fdot2u(w4.y, b4.y, mb[jj]);
      mb[jj] = fdot2u(w4.z, b4.z, mb[jj]);
      mb[jj] = fdot2u(w4.w, b4.w, mb[jj]);
    }
  }
  float accA = 0.f, accB = 0.f;
#pragma unroll
  for (int jj = 0; jj < 32; ++jj) {
    const float w2v = Wp2[w * 32 + jj];
    accA += 0.5f * ma[jj] * (1.0f + erff(ma[jj] * 0.70710678118f)) * w2v;
    accB += 0.5f * mb[jj] * (1.0f + erff(mb[jj] * 0.70710678118f)) * w2v;
  }
  psum[w][l] = accA;
  psum[w][64 + l] = accB;
  __syncthreads();
  if (tid < 128)
    out0[rbase + tid] =
        psum[0][tid] + psum[1][tid] + psum[2][tid] + psum[3][tid] + bp2[0];
}

extern "C" void kernel_launch(void* const* d_in, const int* in_sizes, int n_in,
                              void* d_out, int out_size, void* d_ws, size_t ws_size,
                              hipStream_t stream) {
  const float* x = (const float*)d_in[0];
  const float* ev = (const float*)d_in[1];
  const float* td = (const float*)d_in[2];
  const float* Wproj = (const float*)d_in[3];
  const float* bproj = (const float*)d_in[4];
  const float* Wih = (const float*)d_in[5];
  const float* Whh = (const float*)d_in[6];
  const float* blstm = (const float*)d_in[7];
  const float* Wmk = (const float*)d_in[8];
  const float* bmk = (const float*)d_in[9];
  const float* We = (const float*)d_in[10];
  const float* be = (const float*)d_in[11];
  const float* Whg = (const float*)d_in[12];
  const float* bhg = (const float*)d_in[13];
  const float* decay = (const float*)d_in[14];
  const float* Wp1 = (const float*)d_in[15];
  const float* bp1 = (const float*)d_in[16];
  const float* Wp2 = (const float*)d_in[17];
  const float* bp2 = (const float*)d_in[18];

  float* out0 = (float*)d_out;                // predictions [B,T,1]
  float* out1 = out0 + (size_t)BT;            // features    [B,T,H]
  float* out2 = out1 + (size_t)BT * HH;       // tmdo d1     [B,T,64]

  char* w = (char*)d_ws;
  float* Wfold_f = (float*)w; w += (size_t)65536 * 4;   // 256 KB
  uint* WhV = (uint*)w; w += (size_t)65536 * 4;         // 256 KB
  uint* WhL = (uint*)w; w += (size_t)16384 * 4;         // 64 KB
  uint* XQ = (uint*)w; w += (size_t)20480 * 4;          // 80 KB
  uint* EQ = (uint*)w; w += (size_t)2048 * 4;           // 8 KB
  uint* WQh = (uint*)w; w += (size_t)16384 * 4;         // 64 KB
  float* scales = (float*)w; w += 16 * 4;
  float* bfold = (float*)w; w += 1024 * 4;
  uchar* hB = (uchar*)w; w += (size_t)BB * 256;         // 32 KB int8 h state
  float* cB = (float*)w; w += (size_t)BB * 256 * 4;     // 128 KB c state
  uint* xq = (uint*)w; w += (size_t)BT * 16 * 4;        // 8 MB
  uint* eq = (uint*)w; w += (size_t)BT * 8 * 4;         // 4 MB
  float4* scl = (float4*)w; w += (size_t)BT * 16;       // 2 MB
  uint4* pre = (uint4*)w;                               // remainder: x-preacts

  // size the T-chunk from remaining workspace (pre = 128*steps*256*16 B per chunk)
  size_t used = (size_t)(w - (char*)d_ws);
  size_t avail = (ws_size > used + 4096) ? (ws_size - used - 4096) : 0;
  int steps = TT, lsteps = 10;
  while (steps > 4 && (size_t)BB * (size_t)steps * 256 * 16 > avail) {
    steps >>= 1;
    lsteps--;
  }

  hipLaunchKernelGGL(fold_f32, dim3(256), dim3(256), 0, stream, Wproj, Wih, Wfold_f);
  hipLaunchKernelGGL(bfold_kernel, dim3(4), dim3(256), 0, stream, bproj, Wih, blstm, bfold);
  hipLaunchKernelGGL(quant_all, dim3(5), dim3(1024), 0, stream,
                     Whh, Whg, Wfold_f, Wmk, We, WhV, WhL, XQ, EQ, scales);
  hipLaunchKernelGGL(pack_wp1h, dim3(64), dim3(256), 0, stream, Wp1, WQh);
  hipLaunchKernelGGL(prep_inputs, dim3(BT / 4), dim3(256), 0, stream,
                     x, ev, td, decay, xq, eq, scl);
  hipLaunchKernelGGL(d1_kernel, dim3(8192), dim3(256), 0, stream, x, out2);

  for (int t0 = 0; t0 < TT; t0 += steps) {
    hipLaunchKernelGGL(pre_kernel, dim3(2 * steps), dim3(1024), 0, stream,
                       t0, lsteps, XQ, EQ, scales, bfold, bmk, be, xq, eq, scl, pre);
    hipLaunchKernelGGL(scan3, dim3(BB), dim3(1024), 0, stream,
                       t0, steps, WhV, WhL, scales, bhg, pre, hB, cB, out1);
  }

  hipLaunchKernelGGL(pred3, dim3(BT / 128), dim3(256), 0, stream,
                     out1, WQh, bp1, Wp2, bp2, out0);
}